// Round 8
// baseline (597.412 us; speedup 1.0000x reference)
//
#include <hip/hip_runtime.h>
#include <hip/hip_bf16.h>
#include <math.h>

#define SEQ  512
#define BSZ  128
#define EMBD 128
#define H4   512
#define HD   128
#define NTAG 7
#define BOSX 4
#define EOSX 5
#define NEGC (-10000.0f)

typedef _Float16 h2 __attribute__((ext_vector_type(2)));
typedef _Float16 f16x8 __attribute__((ext_vector_type(8)));
typedef float    f32x4 __attribute__((ext_vector_type(4)));

__device__ __forceinline__ float frcp(float x) { return __builtin_amdgcn_rcpf(x); }

template<int C> __device__ __forceinline__ float dppmovf(float x) {
    return __builtin_bit_cast(float,
        __builtin_amdgcn_update_dpp(0, __builtin_bit_cast(int, x), C, 0xF, 0xF, true));
}
template<int C> __device__ __forceinline__ int dppmovi(int x) {
    return __builtin_amdgcn_update_dpp(0, x, C, 0xF, 0xF, true);
}

// =============== K1: ALL-MFMA BiLSTM (proj batched, recurrence M=1) ==========
// Round-7 post-mortem: moving proj to MFMA cut K1 535->376 (VALU-issue-bound
// confirmed). This round moves the RECURRENCE to MFMA as well: z_h = Whh*h
// as an M=1 matmul with h broadcast into all 16 A-rows (uniform-address LDS
// read = broadcast, conflict-free; all D rows identical -> acc[tt][0]).
// 16 MFMA/step/wave (~80cyc on the 96%-idle MFMA pipe) replaces 64 fdot2 +
// DPP reduce (~280 VALU cyc). whh becomes an MFMA B-operand (AGPR-native,
// no v_accvgpr shuttle); emission = 4 extra MFMA on wave 7 (round-2 trick),
// deleting the wave-0 dot and the chunk-layout h. Cell uses the round-2
// REFCHECK-VERIFIED 4x4 DPP transpose (lane bits 0-1 <-> tile idx tt):
// post-transpose lane owns all 4 gates of unit u = wid*16+(lane&3)*4+(col>>2).
// h state: 128-f16 linear A-frag array, double-buffered; 16 u16 writes/wave.
__global__ __launch_bounds__(512) __attribute__((amdgpu_waves_per_eu(1, 2)))
void bilstm_fused(const int* __restrict__ sen, const float* __restrict__ emb,
                  const float* __restrict__ Wih_f, const float* __restrict__ b_f,
                  const float* __restrict__ Wih_b, const float* __restrict__ b_b,
                  const float* __restrict__ Whh_f, const float* __restrict__ Whh_b,
                  const float* __restrict__ W_out,
                  float* __restrict__ eft, float* __restrict__ ebt)
{
    const int tid = threadIdx.x;
    const int wid = tid >> 6;
    const int lane = tid & 63;
    const int col = lane & 15;                             // MFMA N-col / A-row
    const int kg  = lane >> 4;                             // MFMA K-group
    const bool bk0 = (lane & 1) != 0;
    const bool bk1 = (lane & 2) != 0;
    const int chain = blockIdx.x;
    const int dir = chain & 1;
    const int b = chain >> 1;
    const int t0 = dir ? (SEQ - 1) : 0;
    const int ts = dir ? -1 : 1;

    __shared__ __align__(16) _Float16 xA[2][4][4][16][8];  // x A-frag dbuf, 8 KB
    __shared__ __align__(16) float zb[2][8][512];          // z (proj+bias) dbuf, 32 KB
    __shared__ __align__(16) _Float16 hA[2][128];          // h A-frag dbuf, 512 B

    const float* __restrict__ Wih  = dir ? Wih_b : Wih_f;
    const float* __restrict__ Whh  = dir ? Whh_b : Whh_f;
    const float* __restrict__ bias = dir ? b_b  : b_f;

    // B-fragments: tile tt covers rows R=(wid*4+tt)*16+col, (u,g)=(R>>2,R&3).
    // frag ks holds k = ks*32 + kg*8 + j   [round-2/round-7 verified layout]
    f16x8 bw[4][4], bwh[4][4], be[4];
    float biasv[4];
    #pragma unroll
    for (int tt = 0; tt < 4; ++tt) {
        const int R = (wid * 4 + tt) * 16 + col;
        const int ug = R >> 2;
        const int gg = R & 3;
        #pragma unroll
        for (int ks = 0; ks < 4; ++ks) {
            const float* s1 = Wih + (gg * HD + ug) * EMBD + ks * 32 + kg * 8;
            const float* s2 = Whh + (gg * HD + ug) * HD   + ks * 32 + kg * 8;
            f16x8 v1, v2;
            #pragma unroll
            for (int j = 0; j < 8; ++j) { v1[j] = (_Float16)s1[j]; v2[j] = (_Float16)s2[j]; }
            bw[tt][ks] = v1; bwh[tt][ks] = v2;
        }
        biasv[tt] = bias[gg * HD + ug];
    }
    #pragma unroll
    for (int ks = 0; ks < 4; ++ks) {                       // emission B (used by wave 7)
        f16x8 v;
        #pragma unroll
        for (int j = 0; j < 8; ++j)
            v[j] = (col < NTAG) ? (_Float16)W_out[col * 256 + dir * HD + ks * 32 + kg * 8 + j]
                                : (_Float16)0.f;
        be[ks] = v;
    }

    if (tid < 256) ((_Float16*)hA)[tid] = (_Float16)0.f;   // h=0 both buffers
    {   // zero xA (rows 8..15 never staged; keep MFMA inputs finite)
        unsigned* p = (unsigned*)xA;                       // 2048 dwords
        p[tid] = 0u; p[tid + 512] = 0u; p[tid + 1024] = 0u; p[tid + 1536] = 0u;
    }

    // ---- x staging: window w = rows [8w,8w+8); wave srow stages row 8w+srow,
    // lane sp loads float2 (k=2sp) -> one dword of the A-frag layout ----
    const int srow = wid;
    const int sp = lane;
    float2 sv;                                             // in-flight window regs
    auto sissue = [&](int w) {
        const int row = w * 8 + srow;
        const int tg = t0 + ts * row;
        const int tok = sen[tg * BSZ + b];
        sv = *(const float2*)(emb + (size_t)tok * EMBD + 2 * sp);
    };
    auto swrite = [&](int buf) {
        h2 t; t.x = (_Float16)sv.x; t.y = (_Float16)sv.y;
        *(unsigned*)&xA[buf][sp >> 4][(sp >> 2) & 3][srow][(sp & 3) * 2]
            = __builtin_bit_cast(unsigned, t);
    };

    // ---- batched projection: 16 MFMA -> z rows 0..7 of buffer nb ----
    auto proj = [&](int bufp, int nb) {
        f16x8 ax[4];
        #pragma unroll
        for (int ks = 0; ks < 4; ++ks)
            ax[ks] = *(const f16x8*)&xA[bufp][ks][kg][col][0];
        f32x4 acc[4];
        #pragma unroll
        for (int tt = 0; tt < 4; ++tt) { acc[tt][0]=0.f; acc[tt][1]=0.f; acc[tt][2]=0.f; acc[tt][3]=0.f; }
        #pragma unroll
        for (int ks = 0; ks < 4; ++ks)
            #pragma unroll
            for (int tt = 0; tt < 4; ++tt)
                acc[tt] = __builtin_amdgcn_mfma_f32_16x16x32_f16(ax[ks], bw[tt][ks], acc[tt], 0, 0, 0);
        if (lane < 32) {                                   // D rows 0..7 = time rows
            #pragma unroll
            for (int tt = 0; tt < 4; ++tt)
                #pragma unroll
                for (int r = 0; r < 4; ++r)
                    zb[nb][(lane >> 4) * 4 + r][wid * 64 + tt * 16 + col]
                        = acc[tt][r] + biasv[tt];
        }
    };

    float c = 0.0f;
    float* __restrict__ eX = (dir ? ebt : eft) + (size_t)b * (SEQ * 8);

    // ---- prologue: stage windows 0,1; proj window0 -> zb[0]; window 2 in flight
    sissue(0); swrite(0);
    sissue(1); swrite(1);
    __syncthreads();
    proj(0, 0);                                            // z rows 0..7
    sissue(2);
    __syncthreads();

    // ---- main loop: 64 blocks of 8 steps, ONE barrier/step ----
    for (int base = 0; base < SEQ; base += 8) {
        const int W = base >> 3;
        #pragma unroll
        for (int sl = 0; sl < 8; ++sl) {
            const int s = base + sl;
            const int cur = sl & 1;                        // base even -> s&1 == sl&1
            // h A-frag read: uniform address per ks -> LDS broadcast (free)
            f16x8 ah[4];
            #pragma unroll
            for (int ks = 0; ks < 4; ++ks)
                ah[ks] = *(const f16x8*)&hA[cur][ks * 32 + kg * 8];
            if (sl == 0) {
                if (base <= SEQ - 24) swrite(W & 1);       // window W+2 -> buf W&1
                if (base <= SEQ - 32) sissue(W + 3);       // rows [base+24,base+32)
                if (W < 63) proj((W & 1) ^ 1, (W & 1) ^ 1);// z rows base+8..15
            }
            // recurrence: z_h = Whh*h via M=1 MFMA (all D rows identical)
            f32x4 acc[4];
            #pragma unroll
            for (int tt = 0; tt < 4; ++tt) { acc[tt][0]=0.f; acc[tt][1]=0.f; acc[tt][2]=0.f; acc[tt][3]=0.f; }
            #pragma unroll
            for (int ks = 0; ks < 4; ++ks)
                #pragma unroll
                for (int tt = 0; tt < 4; ++tt)
                    acc[tt] = __builtin_amdgcn_mfma_f32_16x16x32_f16(ah[ks], bwh[tt][ks], acc[tt], 0, 0, 0);
            f32x4 eacc; eacc[0]=0.f; eacc[1]=0.f; eacc[2]=0.f; eacc[3]=0.f;
            if (wid == 7 && s >= 1) {                      // emission e = s-1 from h(s-1)
                #pragma unroll
                for (int ks = 0; ks < 4; ++ks)
                    eacc = __builtin_amdgcn_mfma_f32_16x16x32_f16(ah[ks], be[ks], eacc, 0, 0, 0);
            }
            // activate own gate (g = col&3; gate 2 = tanh via 2*sigma(2z)-1)
            const bool isg = bk1 && !bk0;                  // (lane&3)==2
            float y[4];
            #pragma unroll
            for (int tt = 0; tt < 4; ++tt) {
                const float z = acc[tt][0] + zb[W & 1][sl][wid * 64 + tt * 16 + col];
                const float x2 = isg ? (z + z) : z;
                const float yy = frcp(1.0f + __expf(-x2));
                y[tt] = isg ? (2.0f * yy - 1.0f) : yy;
            }
            // 4x4 DPP transpose (lane bits 0-1 <-> tt)  [round-2 verified]
            const float n0 = bk0 ? dppmovf<0xB1>(y[1]) : y[0];
            const float n1 = bk0 ? y[1] : dppmovf<0xB1>(y[0]);
            const float n2 = bk0 ? dppmovf<0xB1>(y[3]) : y[2];
            const float n3 = bk0 ? y[3] : dppmovf<0xB1>(y[2]);
            const float m0 = bk1 ? dppmovf<0x4E>(n2) : n0;   // i
            const float m2 = bk1 ? n2 : dppmovf<0x4E>(n0);   // g
            const float m1 = bk1 ? dppmovf<0x4E>(n3) : n1;   // f
            const float m3 = bk1 ? n3 : dppmovf<0x4E>(n1);   // o
            c = m1 * c + m0 * m2;                          // redundant x4 over kg
            const float th = 2.0f * frcp(1.0f + __expf(-2.0f * c)) - 1.0f;
            const float h = m3 * th;
            // h write: lane owns unit u = wid*16 + (lane&3)*4 + (col>>2)
            if (kg == 0)
                hA[cur ^ 1][wid * 16 + (lane & 3) * 4 + (lane >> 2)] = (_Float16)h;
            if (wid == 7 && s >= 1 && kg == 0 && col < NTAG)
                eX[(t0 + ts * (s - 1)) * 8 + col] = eacc[0];
            __syncthreads();
        }
    }

    // ---- epilogue: emission e = SEQ-1 from h(SEQ-1) (in hA[0]) ----
    if (wid == 7) {
        f16x8 ah[4];
        #pragma unroll
        for (int ks = 0; ks < 4; ++ks)
            ah[ks] = *(const f16x8*)&hA[0][ks * 32 + kg * 8];
        f32x4 eacc; eacc[0]=0.f; eacc[1]=0.f; eacc[2]=0.f; eacc[3]=0.f;
        #pragma unroll
        for (int ks = 0; ks < 4; ++ks)
            eacc = __builtin_amdgcn_mfma_f32_16x16x32_f16(ah[ks], be[ks], eacc, 0, 0, 0);
        if (kg == 0 && col < NTAG)
            eX[(t0 + ts * (SEQ - 1)) * 8 + col] = eacc[0];
    }
}

// ======================= K2: Viterbi scan + backtrace =======================
// (verbatim round-4 kernel: DPP butterfly argmax, OR-packed 3-bit
// backpointer words, readlane-only bit-chase backtrace)
__global__ __launch_bounds__(256, 1)
void vit_kernel(const float* __restrict__ eft, const float* __restrict__ ebt,
                const float* __restrict__ b_out, const float* __restrict__ trans,
                float* __restrict__ out)
{
    const int b = blockIdx.x;
    const int tid = threadIdx.x;
    __shared__ __align__(16) float ftl[SEQ * 8];
    __shared__ unsigned wordL[SEQ];                        // packed backpointers

    {   // stage ef+eb with all 256 threads
        const float4* sf = (const float4*)(eft + (size_t)b * (SEQ * 8));
        const float4* sb = (const float4*)(ebt + (size_t)b * (SEQ * 8));
        float4* dst = (float4*)ftl;
        #pragma unroll
        for (int i = 0; i < SEQ * 2 / 256; ++i) {
            const int idx = tid + i * 256;
            float4 a = sf[idx];
            const float4 c4 = sb[idx];
            a.x += c4.x; a.y += c4.y; a.z += c4.z; a.w += c4.w;
            dst[idx] = a;
        }
    }
    __syncthreads();

    if (tid < 64) {
        const int lane = tid;
        const int next = lane >> 3;
        const int prev = lane & 7;
        const bool pv = (prev < NTAG);
        const bool nv = (next < NTAG);
        const float trv = (pv && nv) ? (trans[next * NTAG + prev] + b_out[next]) : -3.0e38f;
        float fvp = pv ? ((prev == BOSX) ? 0.0f : NEGC) : -3.0e38f;

        // (max, first-index) combiner is associative+commutative ->
        // any butterfly pairing gives results identical to the shfl version.
        for (int t = 0; t < SEQ; ++t) {
            float mv = fvp + trv;
            int am = prev;
            {   // xor1 (quad_perm)
                const float om = dppmovf<0xB1>(mv); const int oa = dppmovi<0xB1>(am);
                if (om > mv || (om == mv && oa < am)) { mv = om; am = oa; }
            }
            {   // xor2 (quad_perm)
                const float om = dppmovf<0x4E>(mv); const int oa = dppmovi<0x4E>(am);
                if (om > mv || (om == mv && oa < am)) { mv = om; am = oa; }
            }
            {   // quad-pair via row_half_mirror (value quad-uniform by now)
                const float om = dppmovf<0x141>(mv); const int oa = dppmovi<0x141>(am);
                if (om > mv || (om == mv && oa < am)) { mv = om; am = oa; }
            }
            const float fvnew = mv + ftl[t * 8 + next];
            // transpose: fvp[lane] = fvnew(next = prev(lane)); same pattern
            // gathers am so lane holds bptr[next = prev(lane)]
            const float nfv = __shfl(fvnew, (lane & 7) << 3);
            const int   amg = __shfl(am,    (lane & 7) << 3);
            unsigned pw = (unsigned)amg << (3 * prev);     // field for next = prev(lane)
            pw |= (unsigned)dppmovi<0xB1>((int)pw);
            pw |= (unsigned)dppmovi<0x4E>((int)pw);
            pw |= (unsigned)dppmovi<0x141>((int)pw);
            if (lane == 0) wordL[t] = pw;
            fvp = pv ? nfv : -3.0e38f;
        }

        float term = pv ? (fvp + trans[EOSX * NTAG + prev]) : -3.0e38f;
        int am = prev;
        {
            const float om = dppmovf<0xB1>(term); const int oa = dppmovi<0xB1>(am);
            if (om > term || (om == term && oa < am)) { term = om; am = oa; }
        }
        {
            const float om = dppmovf<0x4E>(term); const int oa = dppmovi<0x4E>(am);
            if (om > term || (om == term && oa < am)) { term = om; am = oa; }
        }
        {
            const float om = dppmovf<0x141>(term); const int oa = dppmovi<0x141>(am);
            if (om > term || (om == term && oa < am)) { term = om; am = oa; }
        }
        if (lane == 0) out[b] = term;

        // ---- backtrace: preload packed words, uniform readlane bit-chase ----
        unsigned wd[8];
        #pragma unroll
        for (int c2 = 0; c2 < 8; ++c2) wd[c2] = wordL[c2 * 64 + lane];
        int cur = __builtin_amdgcn_readfirstlane(am);      // uniform terminal tag
        unsigned pr[8];
        #pragma unroll
        for (int c2 = 7; c2 >= 0; --c2) {                  // unrolled: wd/pr static-indexed
            unsigned acc = 0u;
            for (int tt = 63; tt >= 0; --tt) {             // t = c2*64 + tt, descending
                acc = (lane == tt) ? (unsigned)cur : acc;  // path[t] = cur
                const unsigned w = (unsigned)__builtin_amdgcn_readlane((int)wd[c2], tt);
                cur = (int)((w >> (3 * cur)) & 7u);        // cur = bptr[t][cur]
            }
            pr[c2] = acc;
        }
        #pragma unroll
        for (int c2 = 0; c2 < 8; ++c2)
            out[BSZ + (c2 * 64 + lane) * BSZ + b] = (float)pr[c2];
    }
}

// ======================= launch =======================
extern "C" void kernel_launch(void* const* d_in, const int* in_sizes, int n_in,
                              void* d_out, int out_size, void* d_ws, size_t ws_size,
                              hipStream_t stream)
{
    const int*   sen   = (const int*)d_in[0];
    const float* emb   = (const float*)d_in[1];
    const float* Wih_f = (const float*)d_in[2];
    const float* Whh_f = (const float*)d_in[3];
    const float* b_f   = (const float*)d_in[4];
    const float* Wih_b = (const float*)d_in[5];
    const float* Whh_b = (const float*)d_in[6];
    const float* b_b   = (const float*)d_in[7];
    const float* W_out = (const float*)d_in[8];
    const float* b_out = (const float*)d_in[9];
    const float* trans = (const float*)d_in[10];
    float* out = (float*)d_out;

    char* ws = (char*)d_ws;
    const size_t ft_bytes = (size_t)BSZ * SEQ * 8 * 4;    // 2 MB each
    float* eft = (float*)ws;
    float* ebt = (float*)(ws + ft_bytes);

    bilstm_fused<<<dim3(2 * BSZ), dim3(512), 0, stream>>>(
        sen, emb, Wih_f, b_f, Wih_b, b_b, Whh_f, Whh_b, W_out, eft, ebt);
    vit_kernel<<<dim3(BSZ), dim3(256), 0, stream>>>(eft, ebt, b_out, trans, out);
}

// Round 9
// 592.772 us; speedup vs baseline: 1.0078x; 1.0078x over previous
//
#include <hip/hip_runtime.h>
#include <hip/hip_bf16.h>
#include <math.h>

#define SEQ  512
#define BSZ  128
#define EMBD 128
#define H4   512
#define HD   128
#define NTAG 7
#define BOSX 4
#define EOSX 5
#define NEGC (-10000.0f)

typedef _Float16 h2 __attribute__((ext_vector_type(2)));
typedef _Float16 f16x8 __attribute__((ext_vector_type(8)));
typedef float    f32x4 __attribute__((ext_vector_type(4)));

__device__ __forceinline__ float frcp(float x) { return __builtin_amdgcn_rcpf(x); }

template<int C> __device__ __forceinline__ float dppmovf(float x) {
    return __builtin_bit_cast(float,
        __builtin_amdgcn_update_dpp(0, __builtin_bit_cast(int, x), C, 0xF, 0xF, true));
}
template<int C> __device__ __forceinline__ int dppmovi(int x) {
    return __builtin_amdgcn_update_dpp(0, x, C, 0xF, 0xF, true);
}

// step barrier WITHOUT the vmcnt(0)/expcnt drain __syncthreads forces:
// LDS producers (h/zb/xA ds_writes) drain via lgkmcnt(0); global loads/stores
// stay in flight across the barrier (counted vmcnt waits appear at uses).
// sched_barrier(0) fences pin LDS ops on the correct side (rule #18).
__device__ __forceinline__ void step_barrier() {
    __builtin_amdgcn_sched_barrier(0);
    asm volatile("s_waitcnt lgkmcnt(0)" ::: "memory");
    __builtin_amdgcn_s_barrier();
    __builtin_amdgcn_sched_barrier(0);
}

// =============== K1: ALL-MFMA BiLSTM, serial-path-trimmed ====================
// Round-8 post-mortem: issue dropped (VALU 55->40) but time rose -> the step
// is ~75% serial stall, not issue. This round trims the serial path:
// (1) raw lgkm-only barrier (no vmcnt drain: token loads / emission stores
//     no longer stall barriers), (2) emissions re-batched into 8 static regs,
//     flushed once per 8 steps, (3) zb reads for step s+1 prefetched during
//     step s (off the post-MFMA critical path), (4) recurrence MFMA as two
//     2-deep chains + VALU add (halves chained-MFMA latency).
// Layouts unchanged from round-8 (refcheck-passed): A-frag [ks][kg][row][8],
// B per gate-row R=(wid*4+tt)*16+col, M=1 broadcast recurrence, 4x4 DPP
// transpose cell, h as 128-f16 linear A-frag dbuf.
__global__ __launch_bounds__(512) __attribute__((amdgpu_waves_per_eu(1, 2)))
void bilstm_fused(const int* __restrict__ sen, const float* __restrict__ emb,
                  const float* __restrict__ Wih_f, const float* __restrict__ b_f,
                  const float* __restrict__ Wih_b, const float* __restrict__ b_b,
                  const float* __restrict__ Whh_f, const float* __restrict__ Whh_b,
                  const float* __restrict__ W_out,
                  float* __restrict__ eft, float* __restrict__ ebt)
{
    const int tid = threadIdx.x;
    const int wid = tid >> 6;
    const int lane = tid & 63;
    const int col = lane & 15;                             // MFMA N-col / A-row
    const int kg  = lane >> 4;                             // MFMA K-group
    const bool bk0 = (lane & 1) != 0;
    const bool bk1 = (lane & 2) != 0;
    const int chain = blockIdx.x;
    const int dir = chain & 1;
    const int b = chain >> 1;
    const int t0 = dir ? (SEQ - 1) : 0;
    const int ts = dir ? -1 : 1;

    __shared__ __align__(16) _Float16 xA[2][4][4][16][8];  // x A-frag dbuf, 8 KB
    __shared__ __align__(16) float zb[2][8][512];          // z (proj+bias) dbuf, 32 KB
    __shared__ __align__(16) _Float16 hA[2][128];          // h A-frag dbuf, 512 B

    const float* __restrict__ Wih  = dir ? Wih_b : Wih_f;
    const float* __restrict__ Whh  = dir ? Whh_b : Whh_f;
    const float* __restrict__ bias = dir ? b_b  : b_f;

    // B-fragments: tile tt covers rows R=(wid*4+tt)*16+col, (u,g)=(R>>2,R&3).
    // frag ks holds k = ks*32 + kg*8 + j   [round-2/7/8 verified layout]
    f16x8 bw[4][4], bwh[4][4], be[4];
    float biasv[4];
    #pragma unroll
    for (int tt = 0; tt < 4; ++tt) {
        const int R = (wid * 4 + tt) * 16 + col;
        const int ug = R >> 2;
        const int gg = R & 3;
        #pragma unroll
        for (int ks = 0; ks < 4; ++ks) {
            const float* s1 = Wih + (gg * HD + ug) * EMBD + ks * 32 + kg * 8;
            const float* s2 = Whh + (gg * HD + ug) * HD   + ks * 32 + kg * 8;
            f16x8 v1, v2;
            #pragma unroll
            for (int j = 0; j < 8; ++j) { v1[j] = (_Float16)s1[j]; v2[j] = (_Float16)s2[j]; }
            bw[tt][ks] = v1; bwh[tt][ks] = v2;
        }
        biasv[tt] = bias[gg * HD + ug];
    }
    #pragma unroll
    for (int ks = 0; ks < 4; ++ks) {                       // emission B (used by wave 7)
        f16x8 v;
        #pragma unroll
        for (int j = 0; j < 8; ++j)
            v[j] = (col < NTAG) ? (_Float16)W_out[col * 256 + dir * HD + ks * 32 + kg * 8 + j]
                                : (_Float16)0.f;
        be[ks] = v;
    }

    if (tid < 256) ((_Float16*)hA)[tid] = (_Float16)0.f;   // h=0 both buffers
    {   // zero xA (rows 8..15 never staged; keep MFMA inputs finite)
        unsigned* p = (unsigned*)xA;                       // 2048 dwords
        p[tid] = 0u; p[tid + 512] = 0u; p[tid + 1024] = 0u; p[tid + 1536] = 0u;
    }

    // ---- x staging: window w = rows [8w,8w+8); wave srow stages row 8w+srow,
    // lane sp loads float2 (k=2sp) -> one dword of the A-frag layout ----
    const int srow = wid;
    const int sp = lane;
    float2 sv;                                             // in-flight window regs
    auto sissue = [&](int w) {
        const int row = w * 8 + srow;
        const int tg = t0 + ts * row;
        const int tok = sen[tg * BSZ + b];
        sv = *(const float2*)(emb + (size_t)tok * EMBD + 2 * sp);
    };
    auto swrite = [&](int buf) {
        h2 t; t.x = (_Float16)sv.x; t.y = (_Float16)sv.y;
        *(unsigned*)&xA[buf][sp >> 4][(sp >> 2) & 3][srow][(sp & 3) * 2]
            = __builtin_bit_cast(unsigned, t);
    };

    // ---- batched projection: 16 MFMA -> z rows 0..7 of buffer nb ----
    auto proj = [&](int bufp, int nb) {
        f16x8 ax[4];
        #pragma unroll
        for (int ks = 0; ks < 4; ++ks)
            ax[ks] = *(const f16x8*)&xA[bufp][ks][kg][col][0];
        f32x4 acc[4];
        #pragma unroll
        for (int tt = 0; tt < 4; ++tt) { acc[tt][0]=0.f; acc[tt][1]=0.f; acc[tt][2]=0.f; acc[tt][3]=0.f; }
        #pragma unroll
        for (int ks = 0; ks < 4; ++ks)
            #pragma unroll
            for (int tt = 0; tt < 4; ++tt)
                acc[tt] = __builtin_amdgcn_mfma_f32_16x16x32_f16(ax[ks], bw[tt][ks], acc[tt], 0, 0, 0);
        if (lane < 32) {                                   // D rows 0..7 = time rows
            #pragma unroll
            for (int tt = 0; tt < 4; ++tt)
                #pragma unroll
                for (int r = 0; r < 4; ++r)
                    zb[nb][(lane >> 4) * 4 + r][wid * 64 + tt * 16 + col]
                        = acc[tt][r] + biasv[tt];
        }
    };

    float c = 0.0f;
    float ebuf[8];                                         // wave-7 emission regs
    float zqA[4], zqB[4];                                  // z ping-pong (this/next step)
    float* __restrict__ eX = (dir ? ebt : eft) + (size_t)b * (SEQ * 8);

    // ---- prologue: stage windows 0,1; proj window0 -> zb[0]; window 2 in flight
    sissue(0); swrite(0);
    sissue(1); swrite(1);
    __syncthreads();
    proj(0, 0);                                            // z rows 0..7
    sissue(2);
    __syncthreads();
    #pragma unroll
    for (int tt = 0; tt < 4; ++tt)                         // z for step 0
        zqA[tt] = zb[0][0][wid * 64 + tt * 16 + col];

    // ---- main loop: 64 blocks of 8 steps, one lgkm-only barrier/step ----
    for (int base = 0; base < SEQ; base += 8) {
        const int W = base >> 3;
        #pragma unroll
        for (int sl = 0; sl < 8; ++sl) {
            const int s = base + sl;
            const int cur = sl & 1;                        // base even -> s&1 == sl&1
            float* zc = (sl & 1) ? zqB : zqA;              // z for THIS step (prefetched)
            float* zo = (sl & 1) ? zqA : zqB;              // dest: z for step s+1
            // h A-frag read: uniform address per ks -> LDS broadcast (free)
            f16x8 ah[4];
            #pragma unroll
            for (int ks = 0; ks < 4; ++ks)
                ah[ks] = *(const f16x8*)&hA[cur][ks * 32 + kg * 8];
            if (sl == 0) {
                if (base <= SEQ - 24) swrite(W & 1);       // window W+2 -> buf W&1
                if (base <= SEQ - 32) sissue(W + 3);       // rows [base+24,base+32)
                if (W < 63) proj((W & 1) ^ 1, (W & 1) ^ 1);// z rows base+8..15
            }
            // recurrence: z_h = Whh*h via M=1 MFMA, two 2-deep chains per tile
            f32x4 accA[4], accB[4];
            #pragma unroll
            for (int tt = 0; tt < 4; ++tt) {
                accA[tt][0]=0.f; accA[tt][1]=0.f; accA[tt][2]=0.f; accA[tt][3]=0.f;
                accB[tt][0]=0.f; accB[tt][1]=0.f; accB[tt][2]=0.f; accB[tt][3]=0.f;
            }
            #pragma unroll
            for (int tt = 0; tt < 4; ++tt) {
                accA[tt] = __builtin_amdgcn_mfma_f32_16x16x32_f16(ah[0], bwh[tt][0], accA[tt], 0, 0, 0);
                accB[tt] = __builtin_amdgcn_mfma_f32_16x16x32_f16(ah[2], bwh[tt][2], accB[tt], 0, 0, 0);
                accA[tt] = __builtin_amdgcn_mfma_f32_16x16x32_f16(ah[1], bwh[tt][1], accA[tt], 0, 0, 0);
                accB[tt] = __builtin_amdgcn_mfma_f32_16x16x32_f16(ah[3], bwh[tt][3], accB[tt], 0, 0, 0);
            }
            if (wid == 7 && s >= 1) {                      // emission e = s-1 from h(s-1)
                f32x4 eacc; eacc[0]=0.f; eacc[1]=0.f; eacc[2]=0.f; eacc[3]=0.f;
                #pragma unroll
                for (int ks = 0; ks < 4; ++ks)
                    eacc = __builtin_amdgcn_mfma_f32_16x16x32_f16(ah[ks], be[ks], eacc, 0, 0, 0);
                ebuf[sl] = eacc[0];                        // static index (unrolled sl)
            }
            // prefetch z for step s+1 (independent LDS read, overlaps MFMA).
            // sl<7: same buffer/window; sl==7: next window's buffer, written
            // at THIS window's sl==0 proj (barrier-separated -> visible).
            if (s + 1 < SEQ) {
                const int nbuf = (sl == 7) ? ((W & 1) ^ 1) : (W & 1);
                const int nsl = (sl + 1) & 7;
                #pragma unroll
                for (int tt = 0; tt < 4; ++tt)
                    zo[tt] = zb[nbuf][nsl][wid * 64 + tt * 16 + col];
            }
            // activate own gate (g = col&3; gate 2 = tanh via 2*sigma(2z)-1)
            const bool isg = bk1 && !bk0;                  // (lane&3)==2
            float y[4];
            #pragma unroll
            for (int tt = 0; tt < 4; ++tt) {
                const float z = accA[tt][0] + accB[tt][0] + zc[tt];
                const float x2 = isg ? (z + z) : z;
                const float yy = frcp(1.0f + __expf(-x2));
                y[tt] = isg ? (2.0f * yy - 1.0f) : yy;
            }
            // 4x4 DPP transpose (lane bits 0-1 <-> tt)  [round-2 verified]
            const float n0 = bk0 ? dppmovf<0xB1>(y[1]) : y[0];
            const float n1 = bk0 ? y[1] : dppmovf<0xB1>(y[0]);
            const float n2 = bk0 ? dppmovf<0xB1>(y[3]) : y[2];
            const float n3 = bk0 ? y[3] : dppmovf<0xB1>(y[2]);
            const float m0 = bk1 ? dppmovf<0x4E>(n2) : n0;   // i
            const float m2 = bk1 ? n2 : dppmovf<0x4E>(n0);   // g
            const float m1 = bk1 ? dppmovf<0x4E>(n3) : n1;   // f
            const float m3 = bk1 ? n3 : dppmovf<0x4E>(n1);   // o
            c = m1 * c + m0 * m2;                          // redundant x4 over kg
            const float th = 2.0f * frcp(1.0f + __expf(-2.0f * c)) - 1.0f;
            const float h = m3 * th;
            // h write: lane owns unit u = wid*16 + (lane&3)*4 + (col>>2)
            if (kg == 0)
                hA[cur ^ 1][wid * 16 + (lane & 3) * 4 + (lane >> 2)] = (_Float16)h;
            // batched emission flush: e = base-1 .. base+6, once per window
            if (sl == 7 && wid == 7 && kg == 0 && col < NTAG) {
                #pragma unroll
                for (int r = 0; r < 8; ++r) {
                    const int e = base - 1 + r;
                    if (e >= 0) eX[(t0 + ts * e) * 8 + col] = ebuf[r];
                }
            }
            step_barrier();
        }
    }

    // ---- epilogue: emission e = SEQ-1 from h(SEQ-1) (in hA[0]) ----
    if (wid == 7) {
        f16x8 ah[4];
        #pragma unroll
        for (int ks = 0; ks < 4; ++ks)
            ah[ks] = *(const f16x8*)&hA[0][ks * 32 + kg * 8];
        f32x4 eacc; eacc[0]=0.f; eacc[1]=0.f; eacc[2]=0.f; eacc[3]=0.f;
        #pragma unroll
        for (int ks = 0; ks < 4; ++ks)
            eacc = __builtin_amdgcn_mfma_f32_16x16x32_f16(ah[ks], be[ks], eacc, 0, 0, 0);
        if (kg == 0 && col < NTAG)
            eX[(t0 + ts * (SEQ - 1)) * 8 + col] = eacc[0];
    }
}

// ======================= K2: Viterbi scan + backtrace =======================
// (verbatim round-4 kernel: DPP butterfly argmax, OR-packed 3-bit
// backpointer words, readlane-only bit-chase backtrace)
__global__ __launch_bounds__(256, 1)
void vit_kernel(const float* __restrict__ eft, const float* __restrict__ ebt,
                const float* __restrict__ b_out, const float* __restrict__ trans,
                float* __restrict__ out)
{
    const int b = blockIdx.x;
    const int tid = threadIdx.x;
    __shared__ __align__(16) float ftl[SEQ * 8];
    __shared__ unsigned wordL[SEQ];                        // packed backpointers

    {   // stage ef+eb with all 256 threads
        const float4* sf = (const float4*)(eft + (size_t)b * (SEQ * 8));
        const float4* sb = (const float4*)(ebt + (size_t)b * (SEQ * 8));
        float4* dst = (float4*)ftl;
        #pragma unroll
        for (int i = 0; i < SEQ * 2 / 256; ++i) {
            const int idx = tid + i * 256;
            float4 a = sf[idx];
            const float4 c4 = sb[idx];
            a.x += c4.x; a.y += c4.y; a.z += c4.z; a.w += c4.w;
            dst[idx] = a;
        }
    }
    __syncthreads();

    if (tid < 64) {
        const int lane = tid;
        const int next = lane >> 3;
        const int prev = lane & 7;
        const bool pv = (prev < NTAG);
        const bool nv = (next < NTAG);
        const float trv = (pv && nv) ? (trans[next * NTAG + prev] + b_out[next]) : -3.0e38f;
        float fvp = pv ? ((prev == BOSX) ? 0.0f : NEGC) : -3.0e38f;

        // (max, first-index) combiner is associative+commutative ->
        // any butterfly pairing gives results identical to the shfl version.
        for (int t = 0; t < SEQ; ++t) {
            float mv = fvp + trv;
            int am = prev;
            {   // xor1 (quad_perm)
                const float om = dppmovf<0xB1>(mv); const int oa = dppmovi<0xB1>(am);
                if (om > mv || (om == mv && oa < am)) { mv = om; am = oa; }
            }
            {   // xor2 (quad_perm)
                const float om = dppmovf<0x4E>(mv); const int oa = dppmovi<0x4E>(am);
                if (om > mv || (om == mv && oa < am)) { mv = om; am = oa; }
            }
            {   // quad-pair via row_half_mirror (value quad-uniform by now)
                const float om = dppmovf<0x141>(mv); const int oa = dppmovi<0x141>(am);
                if (om > mv || (om == mv && oa < am)) { mv = om; am = oa; }
            }
            const float fvnew = mv + ftl[t * 8 + next];
            // transpose: fvp[lane] = fvnew(next = prev(lane)); same pattern
            // gathers am so lane holds bptr[next = prev(lane)]
            const float nfv = __shfl(fvnew, (lane & 7) << 3);
            const int   amg = __shfl(am,    (lane & 7) << 3);
            unsigned pw = (unsigned)amg << (3 * prev);     // field for next = prev(lane)
            pw |= (unsigned)dppmovi<0xB1>((int)pw);
            pw |= (unsigned)dppmovi<0x4E>((int)pw);
            pw |= (unsigned)dppmovi<0x141>((int)pw);
            if (lane == 0) wordL[t] = pw;
            fvp = pv ? nfv : -3.0e38f;
        }

        float term = pv ? (fvp + trans[EOSX * NTAG + prev]) : -3.0e38f;
        int am = prev;
        {
            const float om = dppmovf<0xB1>(term); const int oa = dppmovi<0xB1>(am);
            if (om > term || (om == term && oa < am)) { term = om; am = oa; }
        }
        {
            const float om = dppmovf<0x4E>(term); const int oa = dppmovi<0x4E>(am);
            if (om > term || (om == term && oa < am)) { term = om; am = oa; }
        }
        {
            const float om = dppmovf<0x141>(term); const int oa = dppmovi<0x141>(am);
            if (om > term || (om == term && oa < am)) { term = om; am = oa; }
        }
        if (lane == 0) out[b] = term;

        // ---- backtrace: preload packed words, uniform readlane bit-chase ----
        unsigned wd[8];
        #pragma unroll
        for (int c2 = 0; c2 < 8; ++c2) wd[c2] = wordL[c2 * 64 + lane];
        int cur = __builtin_amdgcn_readfirstlane(am);      // uniform terminal tag
        unsigned pr[8];
        #pragma unroll
        for (int c2 = 7; c2 >= 0; --c2) {                  // unrolled: wd/pr static-indexed
            unsigned acc = 0u;
            for (int tt = 63; tt >= 0; --tt) {             // t = c2*64 + tt, descending
                acc = (lane == tt) ? (unsigned)cur : acc;  // path[t] = cur
                const unsigned w = (unsigned)__builtin_amdgcn_readlane((int)wd[c2], tt);
                cur = (int)((w >> (3 * cur)) & 7u);        // cur = bptr[t][cur]
            }
            pr[c2] = acc;
        }
        #pragma unroll
        for (int c2 = 0; c2 < 8; ++c2)
            out[BSZ + (c2 * 64 + lane) * BSZ + b] = (float)pr[c2];
    }
}

// ======================= launch =======================
extern "C" void kernel_launch(void* const* d_in, const int* in_sizes, int n_in,
                              void* d_out, int out_size, void* d_ws, size_t ws_size,
                              hipStream_t stream)
{
    const int*   sen   = (const int*)d_in[0];
    const float* emb   = (const float*)d_in[1];
    const float* Wih_f = (const float*)d_in[2];
    const float* Whh_f = (const float*)d_in[3];
    const float* b_f   = (const float*)d_in[4];
    const float* Wih_b = (const float*)d_in[5];
    const float* Whh_b = (const float*)d_in[6];
    const float* b_b   = (const float*)d_in[7];
    const float* W_out = (const float*)d_in[8];
    const float* b_out = (const float*)d_in[9];
    const float* trans = (const float*)d_in[10];
    float* out = (float*)d_out;

    char* ws = (char*)d_ws;
    const size_t ft_bytes = (size_t)BSZ * SEQ * 8 * 4;    // 2 MB each
    float* eft = (float*)ws;
    float* ebt = (float*)(ws + ft_bytes);

    bilstm_fused<<<dim3(2 * BSZ), dim3(512), 0, stream>>>(
        sen, emb, Wih_f, b_f, Wih_b, b_b, Whh_f, Whh_b, W_out, eft, ebt);
    vit_kernel<<<dim3(BSZ), dim3(256), 0, stream>>>(eft, ebt, b_out, trans, out);
}

// Round 10
// 555.160 us; speedup vs baseline: 1.0761x; 1.0678x over previous
//
#include <hip/hip_runtime.h>
#include <hip/hip_bf16.h>
#include <math.h>

#define SEQ  512
#define BSZ  128
#define EMBD 128
#define H4   512
#define HD   128
#define NTAG 7
#define BOSX 4
#define EOSX 5
#define NEGC (-10000.0f)

typedef _Float16 h2 __attribute__((ext_vector_type(2)));
typedef _Float16 f16x8 __attribute__((ext_vector_type(8)));
typedef float    f32x4 __attribute__((ext_vector_type(4)));

__device__ __forceinline__ float frcp(float x) { return __builtin_amdgcn_rcpf(x); }

// f16 dot2: 2 MACs/inst, fp32 accumulate (v_dot2_f32_f16)
__device__ __forceinline__ float fdot2(h2 a, h2 b, float c) {
#if __has_builtin(__builtin_amdgcn_fdot2)
    return __builtin_amdgcn_fdot2(a, b, c, false);
#else
    return c + (float)a.x * (float)b.x + (float)a.y * (float)b.y;
#endif
}

template<int C> __device__ __forceinline__ float dppaddf(float x) {
    const int y = __builtin_amdgcn_update_dpp(0, __builtin_bit_cast(int, x), C, 0xF, 0xF, true);
    return x + __builtin_bit_cast(float, y);
}
template<int C> __device__ __forceinline__ float dppmovf(float x) {
    return __builtin_bit_cast(float,
        __builtin_amdgcn_update_dpp(0, __builtin_bit_cast(int, x), C, 0xF, 0xF, true));
}
template<int C> __device__ __forceinline__ int dppmovi(int x) {
    return __builtin_amdgcn_update_dpp(0, x, C, 0xF, 0xF, true);
}
// k = lane bits {0,1}: full k-reduce = 2 DPP stages
__device__ __forceinline__ float kreduce4(float x) {
    x = dppaddf<0xB1>(x);   // xor bit0
    x = dppaddf<0x4E>(x);   // xor bit1
    return x;
}

// f16 chunk layout for h (recurrence dot operand): chunk k = 32 f16 = 16
// dwords at dword offset 20*k; conflict-free b128 reads (round-1 notes).
#define CH_DW  20
#define ROW_DW 80

// 32-element f16 chunk dot: w[16] half2 x x[16] half2 -> fp32
__device__ __forceinline__ float dot32h(const h2* __restrict__ w, const h2* __restrict__ x) {
    float a = 0.f;
    #pragma unroll
    for (int j = 0; j < 16; ++j) a = fdot2(w[j], x[j], a);
    return a;
}
// load 32 fp32 weights -> 16 half2 (RNE, one-time)
__device__ __forceinline__ void ldwh(h2* w, const float4* wr) {
    #pragma unroll
    for (int j = 0; j < 8; ++j) {
        const float4 f4 = wr[j];
        h2 a; a.x = (_Float16)f4.x; a.y = (_Float16)f4.y;
        h2 b; b.x = (_Float16)f4.z; b.y = (_Float16)f4.w;
        w[2 * j] = a; w[2 * j + 1] = b;
    }
}
__device__ __forceinline__ void unp16(const uint4* p, h2* x) {
    #pragma unroll
    for (int j = 0; j < 4; ++j) {
        x[4 * j]     = __builtin_bit_cast(h2, p[j].x);
        x[4 * j + 1] = __builtin_bit_cast(h2, p[j].y);
        x[4 * j + 2] = __builtin_bit_cast(h2, p[j].z);
        x[4 * j + 3] = __builtin_bit_cast(h2, p[j].w);
    }
}

// step barrier WITHOUT the vmcnt(0)/expcnt drain __syncthreads forces:
// LDS producers (h/zb/xA ds_writes) drain via lgkmcnt(0); global loads/stores
// stay in flight across the barrier (counted vmcnt waits appear at uses).
// sched_barrier(0) fences pin LDS ops on the correct side (rule #18).
// Correctness-proven in round 9 (refcheck pass).
__device__ __forceinline__ void step_barrier() {
    __builtin_amdgcn_sched_barrier(0);
    asm volatile("s_waitcnt lgkmcnt(0)" ::: "memory");
    __builtin_amdgcn_s_barrier();
    __builtin_amdgcn_sched_barrier(0);
}

// =============== K1: round-7 structure (measured optimum, 376 us) ============
// MFMA-batched projection + VALU recurrence. Rounds 8/9 proved the MFMA
// recurrence is net-negative (chained-MFMA latency + acc round-trip on the
// serial path) and that deeper pipelining is null -- round 7 is the bracket
// optimum. Two strictly-local shaves on top:
//  (a) lgkm-only step barrier (no vmcnt drain: emission stores + token loads
//      stay in flight across barriers),
//  (b) zq ping-pong: the per-step dependent zb read moves off the critical
//      path (step s prefetches step s+1's z; window-boundary buffer validity:
//      next window's rows are written at the PREVIOUS window's sl==0 proj,
//      8 barriers before the sl==7 prefetch that first reads them).
__global__ __launch_bounds__(512) __attribute__((amdgpu_waves_per_eu(1, 2)))
void bilstm_fused(const int* __restrict__ sen, const float* __restrict__ emb,
                  const float* __restrict__ Wih_f, const float* __restrict__ b_f,
                  const float* __restrict__ Wih_b, const float* __restrict__ b_b,
                  const float* __restrict__ Whh_f, const float* __restrict__ Whh_b,
                  const float* __restrict__ W_out,
                  float* __restrict__ eft, float* __restrict__ ebt)
{
    const int tid = threadIdx.x;
    const int wid = tid >> 6;
    const int lane = tid & 63;
    const int k = lane & 3;                                // K-chunk / owned gate q
    const int m = lane >> 2;                               // 0..15
    const int u = wid * 16 + m;
    const bool bk0 = (lane & 1) != 0;
    const bool bk1 = (lane & 2) != 0;
    const int col = lane & 15;                             // MFMA N-col / A-row
    const int kg  = lane >> 4;                             // MFMA K-group
    const int chain = blockIdx.x;
    const int dir = chain & 1;
    const int b = chain >> 1;
    const int t0 = dir ? (SEQ - 1) : 0;
    const int ts = dir ? -1 : 1;

    __shared__ __align__(16) _Float16 xA[2][4][4][16][8];  // x A-frag dbuf, 8 KB
    __shared__ __align__(16) float zb[2][8][512];          // z (proj+bias) dbuf, 32 KB
    __shared__ __align__(16) unsigned hdb_u[2 * ROW_DW];   // h double-buffer, f16 chunks

    const float* __restrict__ Wih  = dir ? Wih_b : Wih_f;
    const float* __restrict__ Whh  = dir ? Whh_b : Whh_f;
    const float* __restrict__ bias = dir ? b_b  : b_f;

    // recurrence weights (dot layout) + emission weights
    h2 whh[4][16], wo[16];
    #pragma unroll
    for (int g = 0; g < 4; ++g)
        ldwh(whh[g], (const float4*)(Whh + (g * HD + u) * HD + k * 32));
    {
        const int mm = (m < NTAG) ? m : 0;
        ldwh(wo, (const float4*)(W_out + mm * 256 + dir * HD + k * 32));
    }
    // projection weights as MFMA B-fragments: tile tt covers gate-rows
    // R=(wid*4+tt)*16+col; frag ks holds k = ks*32 + kg*8 + j  [r2/r7 verified]
    f16x8 bw[4][4];
    float biasv[4];
    #pragma unroll
    for (int tt = 0; tt < 4; ++tt) {
        const int R = (wid * 4 + tt) * 16 + col;
        const int ug = R >> 2;
        const int gg = R & 3;
        #pragma unroll
        for (int ks = 0; ks < 4; ++ks) {
            const float* src = Wih + (gg * HD + ug) * EMBD + ks * 32 + kg * 8;
            f16x8 v;
            #pragma unroll
            for (int j = 0; j < 8; ++j) v[j] = (_Float16)src[j];
            bw[tt][ks] = v;
        }
        biasv[tt] = bias[gg * HD + ug];
    }

    if (tid < 2 * ROW_DW) hdb_u[tid] = 0u;                 // h=0
    {   // zero xA (rows 8..15 never staged; keep MFMA inputs finite)
        unsigned* p = (unsigned*)xA;                       // 2048 dwords
        p[tid] = 0u; p[tid + 512] = 0u; p[tid + 1024] = 0u; p[tid + 1536] = 0u;
    }

    // ---- x staging: window w = rows [8w,8w+8); wave srow stages row 8w+srow,
    // lane sp loads float2 (k=2sp) -> one dword of the A-frag layout:
    // ks=sp>>4, kg=(sp>>2)&3, j=(sp&3)*2 ----
    const int srow = wid;
    const int sp = lane;
    float2 sv;                                             // in-flight window regs
    auto sissue = [&](int w) {
        const int row = w * 8 + srow;
        const int tg = t0 + ts * row;
        const int tok = sen[tg * BSZ + b];
        sv = *(const float2*)(emb + (size_t)tok * EMBD + 2 * sp);
    };
    auto swrite = [&](int buf) {
        h2 t; t.x = (_Float16)sv.x; t.y = (_Float16)sv.y;
        *(unsigned*)&xA[buf][sp >> 4][(sp >> 2) & 3][srow][(sp & 3) * 2]
            = __builtin_bit_cast(unsigned, t);
    };

    // ---- batched projection: 16 MFMA -> z rows 0..7 of buffer nb ----
    auto proj = [&](int bufp, int nb) {
        f16x8 ax[4];
        #pragma unroll
        for (int ks = 0; ks < 4; ++ks)
            ax[ks] = *(const f16x8*)&xA[bufp][ks][kg][col][0];
        f32x4 acc[4];
        #pragma unroll
        for (int tt = 0; tt < 4; ++tt) { acc[tt][0]=0.f; acc[tt][1]=0.f; acc[tt][2]=0.f; acc[tt][3]=0.f; }
        #pragma unroll
        for (int ks = 0; ks < 4; ++ks)
            #pragma unroll
            for (int tt = 0; tt < 4; ++tt)
                acc[tt] = __builtin_amdgcn_mfma_f32_16x16x32_f16(ax[ks], bw[tt][ks], acc[tt], 0, 0, 0);
        if (lane < 32) {                                   // D rows 0..7 = time rows
            #pragma unroll
            for (int tt = 0; tt < 4; ++tt)
                #pragma unroll
                for (int r = 0; r < 4; ++r)
                    zb[nb][(lane >> 4) * 4 + r][wid * 64 + tt * 16 + col]
                        = acc[tt][r] + biasv[tt];
        }
    };

    float c = 0.0f, v0 = 0.0f, v1 = 0.0f, v2 = 0.0f, v3 = 0.0f;
    float zqA, zqB;                                        // z ping-pong regs
    float* __restrict__ eX = (dir ? ebt : eft) + (size_t)b * (SEQ * 8);

    // ---- prologue: stage windows 0,1; proj window0 -> zb[0]; window 2 in flight
    sissue(0); swrite(0);
    sissue(1); swrite(1);
    __syncthreads();
    proj(0, 0);                                            // z rows 0..7
    sissue(2);
    __syncthreads();
    zqA = zb[0][0][wid * 64 + lane];                       // z for step 0

    // ---- main loop: 64 blocks of 8 steps, one lgkm-only barrier/step ----
    for (int base = 0; base < SEQ; base += 8) {
        const int W = base >> 3;
        #pragma unroll
        for (int sl = 0; sl < 8; ++sl) {
            const int s = base + sl;
            const int cur = sl & 1;                        // base even -> s&1 == sl&1
            // h-read for this step (chunk k of h_{t-ts})
            uint4 hpk[4];
            {
                const uint4* hr = (const uint4*)(hdb_u + cur * ROW_DW + k * CH_DW);
                #pragma unroll
                for (int j = 0; j < 4; ++j) hpk[j] = hr[j];
            }
            if (sl == 0) {
                if (base <= SEQ - 24) swrite(W & 1);       // window W+2 -> buf W&1
                if (base <= SEQ - 32) sissue(W + 3);       // rows [base+24,base+32)
                if (W < 63) proj((W & 1) ^ 1, (W & 1) ^ 1);// z rows base+8..15
            }
            const float xq = (sl & 1) ? zqB : zqA;         // z for THIS step (prefetched)
            // prefetch z for step s+1 (independent LDS read, overlaps the dots)
            if (s + 1 < SEQ) {
                const int nbuf = (sl == 7) ? ((W & 1) ^ 1) : (W & 1);
                const int nsl = (sl + 1) & 7;
                const float zn = zb[nbuf][nsl][wid * 64 + lane];
                if (sl & 1) zqA = zn; else zqB = zn;
            }
            // recurrence
            h2 hx[16];
            unp16(hpk, hx);
            {
                const float pi = dot32h(whh[0], hx);
                const float pf = dot32h(whh[1], hx);
                const float pg = dot32h(whh[2], hx);
                const float po = dot32h(whh[3], hx);
                const float A = (bk0 ? pf : pi) + dppmovf<0xB1>(bk0 ? pi : pf);
                const float B = (bk0 ? po : pg) + dppmovf<0x4E>(bk0 ? pg : po);
                float z = (bk1 ? B : A) + dppmovf<0x4E>(bk1 ? A : B);
                z += xq;
                // one activation per lane (gate 2 = tanh via 2*sigma(2z)-1)
                const bool isg = bk1 && !bk0;
                const float x2 = isg ? (z + z) : z;
                float y = frcp(1.0f + __expf(-x2));
                y = isg ? (2.0f * y - 1.0f) : y;
                // all-gather the 4 activated gates
                const float r1 = dppmovf<0xB1>(y);
                const float r2 = dppmovf<0x4E>(y);
                const float r3 = dppmovf<0x4E>(r1);
                const float i0 = bk0 ? r1 : y,  i1 = bk0 ? y : r1;
                const float i2 = bk0 ? r3 : r2, i3 = bk0 ? r2 : r3;
                const float gi = bk1 ? i2 : i0;
                const float gf = bk1 ? i3 : i1;
                const float gg2 = bk1 ? i0 : i2;
                const float go = bk1 ? i1 : i3;
                c = gf * c + gi * gg2;                     // redundant across 4 k-lanes
                const float th = 2.0f * frcp(1.0f + __expf(-2.0f * c)) - 1.0f;
                const float h = go * th;
                if (k == 0) {                              // write h as f16 halfword
                    ((unsigned short*)hdb_u)[((cur ^ 1) * ROW_DW + (u >> 5) * CH_DW) * 2 + (u & 31)]
                        = __builtin_bit_cast(unsigned short, (_Float16)h);
                }
            }
            if (wid == 0 && s >= 1) {                      // emission for time e = s-1
                const float ev = kreduce4(dot32h(wo, hx));
                const int e = s - 1;
                const bool mine = (e & 3) == k;            // e uniform, k lane-varying
                const int j = (e >> 2) & 3;
                v0 = (mine && j == 0) ? ev : v0;
                v1 = (mine && j == 1) ? ev : v1;
                v2 = (mine && j == 2) ? ev : v2;
                v3 = (mine && j == 3) ? ev : v3;
                if ((s & 15) == 0 && m < NTAG) {           // flush e in [s-16, s-1]
                    const int eA = s - 16 + k;
                    eX[(t0 + ts * (eA +  0)) * 8 + m] = v0;
                    eX[(t0 + ts * (eA +  4)) * 8 + m] = v1;
                    eX[(t0 + ts * (eA +  8)) * 8 + m] = v2;
                    eX[(t0 + ts * (eA + 12)) * 8 + m] = v3;
                }
            }
            step_barrier();
        }
    }

    // ---- epilogue: s = SEQ -> emission e = SEQ-1 + final flush ----
    {
        h2 hx[16];                                         // h_{last} from hdb[0]
        const uint4* hr = (const uint4*)(hdb_u + k * CH_DW);
        uint4 pk[4];
        #pragma unroll
        for (int j = 0; j < 4; ++j) pk[j] = hr[j];
        unp16(pk, hx);
        if (wid == 0) {
            const float ev = kreduce4(dot32h(wo, hx));
            if (k == 3) v3 = ev;                           // e=511: (e&3)=3, (e>>2)&3=3
            if (m < NTAG) {
                const int eA = SEQ - 16 + k;
                eX[(t0 + ts * (eA +  0)) * 8 + m] = v0;
                eX[(t0 + ts * (eA +  4)) * 8 + m] = v1;
                eX[(t0 + ts * (eA +  8)) * 8 + m] = v2;
                eX[(t0 + ts * (eA + 12)) * 8 + m] = v3;
            }
        }
    }
}

// ======================= K2: Viterbi scan + backtrace =======================
// (verbatim round-4 kernel: DPP butterfly argmax, OR-packed 3-bit
// backpointer words, readlane-only bit-chase backtrace)
__global__ __launch_bounds__(256, 1)
void vit_kernel(const float* __restrict__ eft, const float* __restrict__ ebt,
                const float* __restrict__ b_out, const float* __restrict__ trans,
                float* __restrict__ out)
{
    const int b = blockIdx.x;
    const int tid = threadIdx.x;
    __shared__ __align__(16) float ftl[SEQ * 8];
    __shared__ unsigned wordL[SEQ];                        // packed backpointers

    {   // stage ef+eb with all 256 threads
        const float4* sf = (const float4*)(eft + (size_t)b * (SEQ * 8));
        const float4* sb = (const float4*)(ebt + (size_t)b * (SEQ * 8));
        float4* dst = (float4*)ftl;
        #pragma unroll
        for (int i = 0; i < SEQ * 2 / 256; ++i) {
            const int idx = tid + i * 256;
            float4 a = sf[idx];
            const float4 c4 = sb[idx];
            a.x += c4.x; a.y += c4.y; a.z += c4.z; a.w += c4.w;
            dst[idx] = a;
        }
    }
    __syncthreads();

    if (tid < 64) {
        const int lane = tid;
        const int next = lane >> 3;
        const int prev = lane & 7;
        const bool pv = (prev < NTAG);
        const bool nv = (next < NTAG);
        const float trv = (pv && nv) ? (trans[next * NTAG + prev] + b_out[next]) : -3.0e38f;
        float fvp = pv ? ((prev == BOSX) ? 0.0f : NEGC) : -3.0e38f;

        // (max, first-index) combiner is associative+commutative ->
        // any butterfly pairing gives results identical to the shfl version.
        for (int t = 0; t < SEQ; ++t) {
            float mv = fvp + trv;
            int am = prev;
            {   // xor1 (quad_perm)
                const float om = dppmovf<0xB1>(mv); const int oa = dppmovi<0xB1>(am);
                if (om > mv || (om == mv && oa < am)) { mv = om; am = oa; }
            }
            {   // xor2 (quad_perm)
                const float om = dppmovf<0x4E>(mv); const int oa = dppmovi<0x4E>(am);
                if (om > mv || (om == mv && oa < am)) { mv = om; am = oa; }
            }
            {   // quad-pair via row_half_mirror (value quad-uniform by now)
                const float om = dppmovf<0x141>(mv); const int oa = dppmovi<0x141>(am);
                if (om > mv || (om == mv && oa < am)) { mv = om; am = oa; }
            }
            const float fvnew = mv + ftl[t * 8 + next];
            // transpose: fvp[lane] = fvnew(next = prev(lane)); same pattern
            // gathers am so lane holds bptr[next = prev(lane)]
            const float nfv = __shfl(fvnew, (lane & 7) << 3);
            const int   amg = __shfl(am,    (lane & 7) << 3);
            unsigned pw = (unsigned)amg << (3 * prev);     // field for next = prev(lane)
            pw |= (unsigned)dppmovi<0xB1>((int)pw);
            pw |= (unsigned)dppmovi<0x4E>((int)pw);
            pw |= (unsigned)dppmovi<0x141>((int)pw);
            if (lane == 0) wordL[t] = pw;
            fvp = pv ? nfv : -3.0e38f;
        }

        float term = pv ? (fvp + trans[EOSX * NTAG + prev]) : -3.0e38f;
        int am = prev;
        {
            const float om = dppmovf<0xB1>(term); const int oa = dppmovi<0xB1>(am);
            if (om > term || (om == term && oa < am)) { term = om; am = oa; }
        }
        {
            const float om = dppmovf<0x4E>(term); const int oa = dppmovi<0x4E>(am);
            if (om > term || (om == term && oa < am)) { term = om; am = oa; }
        }
        {
            const float om = dppmovf<0x141>(term); const int oa = dppmovi<0x141>(am);
            if (om > term || (om == term && oa < am)) { term = om; am = oa; }
        }
        if (lane == 0) out[b] = term;

        // ---- backtrace: preload packed words, uniform readlane bit-chase ----
        unsigned wd[8];
        #pragma unroll
        for (int c2 = 0; c2 < 8; ++c2) wd[c2] = wordL[c2 * 64 + lane];
        int cur = __builtin_amdgcn_readfirstlane(am);      // uniform terminal tag
        unsigned pr[8];
        #pragma unroll
        for (int c2 = 7; c2 >= 0; --c2) {                  // unrolled: wd/pr static-indexed
            unsigned acc = 0u;
            for (int tt = 63; tt >= 0; --tt) {             // t = c2*64 + tt, descending
                acc = (lane == tt) ? (unsigned)cur : acc;  // path[t] = cur
                const unsigned w = (unsigned)__builtin_amdgcn_readlane((int)wd[c2], tt);
                cur = (int)((w >> (3 * cur)) & 7u);        // cur = bptr[t][cur]
            }
            pr[c2] = acc;
        }
        #pragma unroll
        for (int c2 = 0; c2 < 8; ++c2)
            out[BSZ + (c2 * 64 + lane) * BSZ + b] = (float)pr[c2];
    }
}

// ======================= launch =======================
extern "C" void kernel_launch(void* const* d_in, const int* in_sizes, int n_in,
                              void* d_out, int out_size, void* d_ws, size_t ws_size,
                              hipStream_t stream)
{
    const int*   sen   = (const int*)d_in[0];
    const float* emb   = (const float*)d_in[1];
    const float* Wih_f = (const float*)d_in[2];
    const float* Whh_f = (const float*)d_in[3];
    const float* b_f   = (const float*)d_in[4];
    const float* Wih_b = (const float*)d_in[5];
    const float* Whh_b = (const float*)d_in[6];
    const float* b_b   = (const float*)d_in[7];
    const float* W_out = (const float*)d_in[8];
    const float* b_out = (const float*)d_in[9];
    const float* trans = (const float*)d_in[10];
    float* out = (float*)d_out;

    char* ws = (char*)d_ws;
    const size_t ft_bytes = (size_t)BSZ * SEQ * 8 * 4;    // 2 MB each
    float* eft = (float*)ws;
    float* ebt = (float*)(ws + ft_bytes);

    bilstm_fused<<<dim3(2 * BSZ), dim3(512), 0, stream>>>(
        sen, emb, Wih_f, b_f, Wih_b, b_b, Whh_f, Whh_b, W_out, eft, ebt);
    vit_kernel<<<dim3(BSZ), dim3(256), 0, stream>>>(eft, ebt, b_out, trans, out);
}